// Round 12
// baseline (1158.551 us; speedup 1.0000x reference)
//
#include <hip/hip_runtime.h>
#include <math.h>

// ---------------- problem constants ----------------
static constexpr int BB = 4;
static constexpr int IMG_H = 512, IMG_W = 1408;
static constexpr int C1 = 32, H1C = 256, W1C = 704;
static constexpr int C2 = 64, H2C = 128, W2C = 352;
static constexpr int C3 = 96, H3C = 64,  W3C = 176;
static constexpr int NPIX = H3C * W3C;          // 11264
static constexpr int KTOP = 200;
static constexpr int BEV = 512;

// ---------------- workspace layout (floats) ----------------
static constexpr size_t SZ_X1   = (size_t)BB * C1 * H1C * W1C;
static constexpr size_t SZ_X2   = (size_t)BB * C2 * H2C * W2C;
static constexpr size_t SZ_HEAD = (size_t)BB * C3 * H3C * W3C;
static constexpr size_t OFF_X1   = 0;
static constexpr size_t OFF_X2   = SZ_X1;
static constexpr size_t OFF_F    = OFF_X2 + SZ_X2;
static constexpr size_t OFF_PROB = OFF_F + SZ_HEAD;
static constexpr size_t OFF_DEP  = OFF_PROB + (size_t)BB * NPIX;
static constexpr size_t OFF_HMA  = OFF_DEP + (size_t)BB * NPIX;   // hm-logit accum
static constexpr size_t OFF_DLA  = OFF_HMA + (size_t)BB * NPIX;   // depth-logit accum
static constexpr size_t OFF_BEV  = OFF_DLA + (size_t)BB * NPIX;   // float [BB*512*512]

// BN eval scale: 1/sqrt(1 + 1e-5)
static constexpr float BN_SCALE = 0.99999500003749973f;

// ---------------- tiled conv 3x3 (+BN+ReLU) with double-buffered LDS staging ----
// Block: 256 threads = 4 waves, 64 output columns (lane = ox), one output row.
// OCG splits the OC dimension across OCG blocks. Staging is reg-issued early
// and committed to the alternate LDS buffer after compute (1 barrier/chunk).
// EPI: 0 = store BN+ReLU conv output (A-side only).
//      2 = FUSED HEADS: two independent 3x3 convs (A=Wh1,B=Wd1) over the same
//          staged input; BN+ReLU each; dot with w2A/w2B over this block's
//          channels; atomicAdd into outA/outB (zero-initialized; exactly OCG=2
//          commutative f32 adds per pixel = deterministic).
template <int CIN, int STRIDE, int OC, int CC, int EPI, int OCG>
__global__ __launch_bounds__(256) void conv3x3_tiled(
        const float* __restrict__ in, const float* __restrict__ wg,
        const float* __restrict__ gam, const float* __restrict__ bet,
        float* __restrict__ out, const float* __restrict__ w2,
        const float* __restrict__ wgB, const float* __restrict__ gamB,
        const float* __restrict__ betB, float* __restrict__ outB,
        const float* __restrict__ w2B,
        int H, int W, int OH, int OW) {
    constexpr int OCW = OC / (4 * OCG);
    constexpr int SPAN = STRIDE * 64 + 2;     // 130 (s2) / 66 (s1)
    constexpr int ELEMS = CC * 3 * SPAN;
    constexpr int NLD = (ELEMS + 255) / 256;
    constexpr int NCH = CIN / CC;
    constexpr int NRED = (EPI == 2) ? 2 : 1;
    __shared__ float lds[2][ELEMS];
    __shared__ float red[NRED][4][64];

    const int xt = blockIdx.x / OCG, g = blockIdx.x % OCG;
    const int oy = blockIdx.y, b = blockIdx.z;
    const int t = threadIdx.x;
    const int lane = t & 63, wave = t >> 6;
    const int ox0 = xt * 64;
    const int ox = ox0 + lane;
    const int gx0 = ox0 * STRIDE - 1;
    const int li = STRIDE * lane;

    const int woc0 = (__builtin_amdgcn_readfirstlane(wave) + 4 * g) * OCW;
    const float* wbase = wg + (size_t)woc0 * CIN * 9;
    const float* wbaseB = (EPI == 2) ? (wgB + (size_t)woc0 * CIN * 9) : nullptr;

    float acc[OCW];
    float accB[(EPI == 2) ? OCW : 1];
#pragma unroll
    for (int j = 0; j < OCW; ++j) acc[j] = 0.f;
    if constexpr (EPI == 2) {
#pragma unroll
        for (int j = 0; j < OCW; ++j) accB[j] = 0.f;
    }

    float st[NLD];
    auto issue = [&](int cin0) {
#pragma unroll
        for (int l = 0; l < NLD; ++l) {
            const int i = t + l * 256;
            float v = 0.f;
            if (i < ELEMS) {
                const int cc = i / (3 * SPAN);
                const int rem = i % (3 * SPAN);
                const int r = rem / SPAN, x = rem % SPAN;
                const int gx = gx0 + x;
                const int iy = oy * STRIDE + r - 1;
                if (gx >= 0 && gx < W && iy >= 0 && iy < H)
                    v = in[((size_t)(b * CIN + cin0 + cc) * H + iy) * W + gx];
            }
            st[l] = v;
        }
    };
    auto commit = [&](int buf) {
#pragma unroll
        for (int l = 0; l < NLD; ++l) {
            const int i = t + l * 256;
            if (i < ELEMS) lds[buf][i] = st[l];
        }
    };

    issue(0);
    commit(0);
    __syncthreads();
    for (int k = 0; k < NCH; ++k) {
        const int cur = k & 1;
        if (k + 1 < NCH) issue((k + 1) * CC);
        const float* __restrict__ L = lds[cur];
#pragma unroll 2
        for (int cc = 0; cc < CC; ++cc) {
            const int cin = k * CC + cc;
#pragma unroll
            for (int kh = 0; kh < 3; ++kh) {
                const float v0 = L[(cc * 3 + kh) * SPAN + li + 0];
                const float v1 = L[(cc * 3 + kh) * SPAN + li + 1];
                const float v2 = L[(cc * 3 + kh) * SPAN + li + 2];
                const float* wp = wbase + cin * 9 + kh * 3;
#pragma unroll
                for (int j = 0; j < OCW; ++j) {
                    const float* wj = wp + (size_t)j * CIN * 9;
                    acc[j] = fmaf(v0, wj[0], acc[j]);
                    acc[j] = fmaf(v1, wj[1], acc[j]);
                    acc[j] = fmaf(v2, wj[2], acc[j]);
                }
                if constexpr (EPI == 2) {
                    const float* wpB = wbaseB + cin * 9 + kh * 3;
#pragma unroll
                    for (int j = 0; j < OCW; ++j) {
                        const float* wjB = wpB + (size_t)j * CIN * 9;
                        accB[j] = fmaf(v0, wjB[0], accB[j]);
                        accB[j] = fmaf(v1, wjB[1], accB[j]);
                        accB[j] = fmaf(v2, wjB[2], accB[j]);
                    }
                }
            }
        }
        if (k + 1 < NCH) commit((k + 1) & 1);
        __syncthreads();
    }

    const bool lane_ok = (ox < OW);
    if constexpr (EPI == 0) {
#pragma unroll
        for (int j = 0; j < OCW; ++j) {
            const int oc = woc0 + j;
            const float s = gam[oc] * BN_SCALE;
            const float bb = bet[oc];
            const float r = fmaxf(fmaf(acc[j], s, bb), 0.f);
            if (lane_ok)
                out[((size_t)(b * OC + oc) * OH + oy) * OW + ox] = r;
        }
    } else {
        float pA = 0.f, pB = 0.f;
#pragma unroll
        for (int j = 0; j < OCW; ++j) {
            const int oc = woc0 + j;
            const float rA = fmaxf(fmaf(acc[j], gam[oc] * BN_SCALE, bet[oc]), 0.f);
            pA = fmaf(rA, w2[oc], pA);
            const float rB = fmaxf(fmaf(accB[j], gamB[oc] * BN_SCALE, betB[oc]), 0.f);
            pB = fmaf(rB, w2B[oc], pB);
        }
        red[0][wave][lane] = pA;
        red[1][wave][lane] = pB;
        __syncthreads();
        if (wave == 0 && lane_ok) {
            const size_t pix = (size_t)b * NPIX + (size_t)oy * OW + ox;
            const float sA = red[0][0][lane] + red[0][1][lane] + red[0][2][lane] + red[0][3][lane];
            atomicAdd(&out[pix], sA);
            const float sB = red[1][0][lane] + red[1][1][lane] + red[1][2][lane] + red[1][3][lane];
            atomicAdd(&outB[pix], sB);
        }
    }
}

// ---------------- zero init: bev + head accumulators ----------------
__global__ void zero_init(float* __restrict__ bev, float* __restrict__ hma,
                          float* __restrict__ dla) {
    int i = blockIdx.x * blockDim.x + threadIdx.x;
    if (i < BB * BEV * BEV) bev[i] = 0.0f;
    if (i < BB * NPIX) { hma[i] = 0.0f; dla[i] = 0.0f; }
}

// ---------------- head finish: bias + sigmoid / depth transform ----------------
__global__ void heads_finish(const float* __restrict__ hma, const float* __restrict__ dla,
                             const float* __restrict__ bh2, const float* __restrict__ bd2,
                             float* __restrict__ out_hm, float* __restrict__ out_depth,
                             float* __restrict__ prob, float* __restrict__ depw) {
    int i = blockIdx.x * blockDim.x + threadIdx.x;
    if (i >= BB * NPIX) return;
    const float hm = hma[i] + bh2[0];
    out_hm[i] = hm;
    prob[i] = 1.0f / (1.0f + expf(-hm));
    const float dl = dla[i] + bd2[0];
    const float dep = 1.0f + (1.0f / (1.0f + expf(-dl))) * 79.0f;
    out_depth[i] = dep;
    depw[i] = dep;
}

// ---------------- select top-K SET by value-bisection + fused projection/splat ----
__global__ __launch_bounds__(1024) void select_splat(
        const float* __restrict__ prob, const float* __restrict__ depth,
        const float* __restrict__ camP, const float* __restrict__ camT,
        float* __restrict__ bev) {
    const int b = blockIdx.x;
    const int tid = threadIdx.x;
    const int lane = tid & 63, wave = tid >> 6;
    __shared__ unsigned sv[NPIX];
    __shared__ unsigned wcnt[16];
    __shared__ unsigned scan_w[16];
    __shared__ unsigned bcast;
    __shared__ int list[KTOP];
    __shared__ int nsel;

    for (int i = tid; i < NPIX; i += 1024) sv[i] = __float_as_uint(prob[(size_t)b * NPIX + i]);
    if (tid == 0) nsel = 0;
    __syncthreads();

    auto countGE = [&](unsigned t) -> unsigned {
        unsigned c = 0;
        for (int i = tid; i < NPIX; i += 1024) c += (sv[i] >= t) ? 1u : 0u;
#pragma unroll
        for (int off = 32; off; off >>= 1) c += __shfl_xor((int)c, off, 64);
        if (lane == 0) wcnt[wave] = c;
        __syncthreads();
        if (tid == 0) {
            unsigned tot = 0;
            for (int w = 0; w < 16; ++w) tot += wcnt[w];
            bcast = tot;
        }
        __syncthreads();
        unsigned tot = bcast;
        __syncthreads();
        return tot;
    };

    const unsigned THRB = 0x3E19999Au;          // __float_as_uint(0.15f)
    unsigned tstrict;
    unsigned need = 0;
    const unsigned c_thr = countGE(THRB);
    if (c_thr <= (unsigned)KTOP) {
        tstrict = THRB - 1u;
    } else {
        unsigned lo = THRB, hi = 0x3F800000u;
        while (lo < hi) {
            unsigned mid = lo + (hi - lo + 1u) / 2u;
            unsigned c = countGE(mid);
            if (c >= (unsigned)KTOP) lo = mid; else hi = mid - 1u;
        }
        tstrict = lo;
        need = (unsigned)KTOP - countGE(lo + 1u);
    }

    for (int i = tid; i < NPIX; i += 1024)
        if (sv[i] > tstrict) { int p = atomicAdd(&nsel, 1); list[p] = i; }
    __syncthreads();

    if (need > 0) {
        const unsigned tv = tstrict;
        const int CH = NPIX / 1024;
        const int i0 = tid * CH, i1 = i0 + CH;
        unsigned cnt = 0;
        for (int i = i0; i < i1; ++i) cnt += (sv[i] == tv) ? 1u : 0u;
        unsigned inc = cnt;
#pragma unroll
        for (int off = 1; off < 64; off <<= 1) {
            unsigned o = __shfl_up((int)inc, off, 64);
            if (lane >= off) inc += o;
        }
        if (lane == 63) scan_w[wave] = inc;
        __syncthreads();
        if (tid == 0) {
            unsigned s = 0;
            for (int w = 0; w < 16; ++w) { unsigned x = scan_w[w]; scan_w[w] = s; s += x; }
        }
        __syncthreads();
        unsigned r = inc - cnt + scan_w[wave];
        for (int i = i0; i < i1; ++i) {
            if (sv[i] == tv) {
                if (r < need) { int p = atomicAdd(&nsel, 1); list[p] = i; }
                ++r;
            }
        }
        __syncthreads();
    }

    const int ns = nsel;
    if (tid < ns) {
        const int idx = list[tid];
        const float score = __uint_as_float(sv[idx]);
        const int ys = idx / W3C, xs = idx % W3C;
        const float d = depth[(size_t)b * NPIX + idx];
        const float u = ((float)xs + 0.5f) * 8.0f;
        const float v = ((float)ys + 0.5f) * 8.0f;
        const float* P = camP + b * 12;
        const float fx = fmaxf(P[0], 1e-4f), fy = fmaxf(P[5], 1e-4f);
        const float cx = P[2], cy = P[6], tx = P[3], ty = P[7];
        const float x_cam = (u * d - cx * d - tx) / fx;
        const float y_cam = (v * d - cy * d - ty) / fy;
        const float* T = camT + b * 16;
        const float lx = T[0] * x_cam + T[1] * y_cam + T[2] * d + T[3];
        const float ly = T[4] * x_cam + T[5] * y_cam + T[6] * d + T[7];
        const int gx = (int)floorf((lx - (-51.2f)) / 0.2f);
        const int gy = (int)floorf((ly - (-51.2f)) / 0.2f);
        if (gx >= 0 && gx < BEV && gy >= 0 && gy < BEV) {
            int* bb = (int*)(bev + (size_t)b * BEV * BEV);
#pragma unroll
            for (int dy = -2; dy <= 2; ++dy) {
                const int iy = gy + dy;
                if (iy < 0 || iy >= BEV) continue;
#pragma unroll
                for (int dx = -2; dx <= 2; ++dx) {
                    const int ix = gx + dx;
                    if (ix < 0 || ix >= BEV) continue;
                    const float g = expf((float)(-(dy * dy + dx * dx)) / 1.3888888888888890f);
                    atomicMax(&bb[iy * BEV + ix], __float_as_int(score * g));
                }
            }
        }
    }
}

// ---------------- clip + logit ----------------
__global__ void bev_finish(const float* __restrict__ bev, float* __restrict__ out_logits,
                           float* __restrict__ out_prob) {
    int i = blockIdx.x * blockDim.x + threadIdx.x;
    if (i >= BB * BEV * BEV) return;
    float p = bev[i];
    p = fminf(fmaxf(p, 1e-4f), 0.9999f);
    out_logits[i] = logf(p) - log1pf(-p);
    out_prob[i] = p;
}

// ---------------- launcher ----------------
extern "C" void kernel_launch(void* const* d_in, const int* in_sizes, int n_in,
                              void* d_out, int out_size, void* d_ws, size_t ws_size,
                              hipStream_t stream) {
    (void)in_sizes; (void)n_in; (void)out_size; (void)ws_size;
    const float* image = (const float*)d_in[0];
    const float* camP  = (const float*)d_in[1];
    const float* camT  = (const float*)d_in[2];
    const float* W1  = (const float*)d_in[3];
    const float* g1  = (const float*)d_in[4];
    const float* b1  = (const float*)d_in[5];
    const float* W2  = (const float*)d_in[6];
    const float* g2  = (const float*)d_in[7];
    const float* b2  = (const float*)d_in[8];
    const float* W3  = (const float*)d_in[9];
    const float* g3  = (const float*)d_in[10];
    const float* b3  = (const float*)d_in[11];
    const float* Wh1 = (const float*)d_in[12];
    const float* gh1 = (const float*)d_in[13];
    const float* bh1 = (const float*)d_in[14];
    const float* Wh2 = (const float*)d_in[15];
    const float* bh2 = (const float*)d_in[16];
    const float* Wd1 = (const float*)d_in[17];
    const float* gd1 = (const float*)d_in[18];
    const float* bd1 = (const float*)d_in[19];
    const float* Wd2 = (const float*)d_in[20];
    const float* bd2 = (const float*)d_in[21];

    float* ws = (float*)d_ws;
    float* x1    = ws + OFF_X1;
    float* x2    = ws + OFF_X2;
    float* feats = ws + OFF_F;
    float* prob  = ws + OFF_PROB;
    float* depw  = ws + OFF_DEP;
    float* hma   = ws + OFF_HMA;
    float* dla   = ws + OFF_DLA;
    float* bev   = ws + OFF_BEV;

    float* out       = (float*)d_out;
    float* out_hm    = out;                                // [4,1,64,176]
    float* out_depth = out + (size_t)BB * NPIX;            // [4,1,64,176]
    float* out_lg    = out + (size_t)2 * BB * NPIX;        // [4,1,512,512]
    float* out_pr    = out_lg + (size_t)BB * BEV * BEV;    // [4,1,512,512]

    const int TPB = 256;
    // zero bev + head accumulators first (ws is poisoned before every launch)
    zero_init<<<(BB * BEV * BEV + TPB - 1) / TPB, TPB, 0, stream>>>(bev, hma, dla);

    // conv1: 3 -> 32, s2 (single cin chunk)
    conv3x3_tiled<3, 2, 32, 3, 0, 1><<<dim3(11, H1C, BB), 256, 0, stream>>>(
        image, W1, g1, b1, x1, nullptr, nullptr, nullptr, nullptr, nullptr, nullptr,
        IMG_H, IMG_W, H1C, W1C);
    // conv2: 32 -> 64, s2
    conv3x3_tiled<32, 2, 64, 8, 0, 1><<<dim3(6, H2C, BB), 256, 0, stream>>>(
        x1, W2, g2, b2, x2, nullptr, nullptr, nullptr, nullptr, nullptr, nullptr,
        H1C, W1C, H2C, W2C);
    // conv3: 64 -> 96, s2, oc-split x2 for occupancy
    conv3x3_tiled<64, 2, 96, 8, 0, 2><<<dim3(3 * 2, H3C, BB), 256, 0, stream>>>(
        x2, W3, g3, b3, feats, nullptr, nullptr, nullptr, nullptr, nullptr, nullptr,
        H2C, W2C, H3C, W3C);
    // FUSED heads: 96 -> (96 -> 1x1) x2 over one staged feats tile
    conv3x3_tiled<96, 1, 96, 8, 2, 2><<<dim3(3 * 2, H3C, BB), 256, 0, stream>>>(
        feats, Wh1, gh1, bh1, hma, Wh2, Wd1, gd1, bd1, dla, Wd2,
        H3C, W3C, H3C, W3C);
    // bias + sigmoid/depth transforms
    heads_finish<<<(BB * NPIX + TPB - 1) / TPB, TPB, 0, stream>>>(
        hma, dla, bh2, bd2, out_hm, out_depth, prob, depw);

    // BEV: select+splat -> finish
    select_splat<<<BB, 1024, 0, stream>>>(prob, depw, camP, camT, bev);
    bev_finish<<<(BB * BEV * BEV + TPB - 1) / TPB, TPB, 0, stream>>>(bev, out_lg, out_pr);
}

// Round 13
// 951.840 us; speedup vs baseline: 1.2172x; 1.2172x over previous
//
#include <hip/hip_runtime.h>
#include <math.h>

// ---------------- problem constants ----------------
static constexpr int BB = 4;
static constexpr int IMG_H = 512, IMG_W = 1408;
static constexpr int C1 = 32, H1C = 256, W1C = 704;
static constexpr int C2 = 64, H2C = 128, W2C = 352;
static constexpr int C3 = 96, H3C = 64,  W3C = 176;
static constexpr int NPIX = H3C * W3C;          // 11264
static constexpr int KTOP = 200;
static constexpr int BEV = 512;

// ---------------- workspace layout (floats) ----------------
static constexpr size_t SZ_X1   = (size_t)BB * C1 * H1C * W1C;
static constexpr size_t SZ_X2   = (size_t)BB * C2 * H2C * W2C;
static constexpr size_t SZ_HEAD = (size_t)BB * C3 * H3C * W3C;
static constexpr size_t OFF_X1   = 0;
static constexpr size_t OFF_X2   = SZ_X1;
static constexpr size_t OFF_F    = OFF_X2 + SZ_X2;
static constexpr size_t OFF_PROB = OFF_F + SZ_HEAD;
static constexpr size_t OFF_DEP  = OFF_PROB + (size_t)BB * NPIX;
static constexpr size_t OFF_HMA  = OFF_DEP + (size_t)BB * NPIX;   // hm-logit accum
static constexpr size_t OFF_DLA  = OFF_HMA + (size_t)BB * NPIX;   // depth-logit accum
static constexpr size_t OFF_BEV  = OFF_DLA + (size_t)BB * NPIX;   // float [BB*512*512]

// BN eval scale: 1/sqrt(1 + 1e-5)
static constexpr float BN_SCALE = 0.99999500003749973f;

// ---------------- tiled conv 3x3 (+BN+ReLU) with double-buffered LDS staging ----
// Block: 256 threads = 4 waves, 64 output columns (lane = ox), one output row.
// OCG splits the OC dimension across OCG blocks (wave of block g owns
// (4g+wave)*OCW .. +OCW channels). Staging is reg-issued early and committed
// to the alternate LDS buffer after compute -> 1 barrier/chunk.
// EPI: 0 = store BN+ReLU conv output.
//      1 = BN+ReLU -> dot with w2 over this block's channels -> atomicAdd(out)
//          (out zero-initialized; exactly OCG=2 commutative f32 adds = deterministic)
// NOTE (R12 post-mortem): fusing both heads into one kernel (dual acc/weights)
// REGRESSED 430->642 us — inner-loop instruction bloat + VGPR growth beat the
// staging savings. Keep heads as two EPI=1 launches; CC=16 halves their
// barrier/staging-chunk count instead.
template <int CIN, int STRIDE, int OC, int CC, int EPI, int OCG>
__global__ __launch_bounds__(256) void conv3x3_tiled(
        const float* __restrict__ in, const float* __restrict__ wg,
        const float* __restrict__ gam, const float* __restrict__ bet,
        float* __restrict__ out, const float* __restrict__ w2,
        int H, int W, int OH, int OW) {
    constexpr int OCW = OC / (4 * OCG);
    constexpr int SPAN = STRIDE * 64 + 2;     // 130 (s2) / 66 (s1)
    constexpr int ELEMS = CC * 3 * SPAN;
    constexpr int NLD = (ELEMS + 255) / 256;
    constexpr int NCH = CIN / CC;
    __shared__ float lds[2][ELEMS];
    __shared__ float red[4][64];

    const int xt = blockIdx.x / OCG, g = blockIdx.x % OCG;
    const int oy = blockIdx.y, b = blockIdx.z;
    const int t = threadIdx.x;
    const int lane = t & 63, wave = t >> 6;
    const int ox0 = xt * 64;
    const int ox = ox0 + lane;
    const int gx0 = ox0 * STRIDE - 1;
    const int li = STRIDE * lane;

    const int woc0 = (__builtin_amdgcn_readfirstlane(wave) + 4 * g) * OCW;
    const float* wbase = wg + (size_t)woc0 * CIN * 9;

    float acc[OCW];
#pragma unroll
    for (int j = 0; j < OCW; ++j) acc[j] = 0.f;

    float st[NLD];
    auto issue = [&](int cin0) {
#pragma unroll
        for (int l = 0; l < NLD; ++l) {
            const int i = t + l * 256;
            float v = 0.f;
            if (i < ELEMS) {
                const int cc = i / (3 * SPAN);
                const int rem = i % (3 * SPAN);
                const int r = rem / SPAN, x = rem % SPAN;
                const int gx = gx0 + x;
                const int iy = oy * STRIDE + r - 1;
                if (gx >= 0 && gx < W && iy >= 0 && iy < H)
                    v = in[((size_t)(b * CIN + cin0 + cc) * H + iy) * W + gx];
            }
            st[l] = v;
        }
    };
    auto commit = [&](int buf) {
#pragma unroll
        for (int l = 0; l < NLD; ++l) {
            const int i = t + l * 256;
            if (i < ELEMS) lds[buf][i] = st[l];
        }
    };

    issue(0);
    commit(0);
    __syncthreads();
    for (int k = 0; k < NCH; ++k) {
        const int cur = k & 1;
        if (k + 1 < NCH) issue((k + 1) * CC);
        const float* __restrict__ L = lds[cur];
#pragma unroll 2
        for (int cc = 0; cc < CC; ++cc) {
            const int cin = k * CC + cc;
#pragma unroll
            for (int kh = 0; kh < 3; ++kh) {
                const float v0 = L[(cc * 3 + kh) * SPAN + li + 0];
                const float v1 = L[(cc * 3 + kh) * SPAN + li + 1];
                const float v2 = L[(cc * 3 + kh) * SPAN + li + 2];
                const float* wp = wbase + cin * 9 + kh * 3;
#pragma unroll
                for (int j = 0; j < OCW; ++j) {
                    const float* wj = wp + (size_t)j * CIN * 9;
                    acc[j] = fmaf(v0, wj[0], acc[j]);
                    acc[j] = fmaf(v1, wj[1], acc[j]);
                    acc[j] = fmaf(v2, wj[2], acc[j]);
                }
            }
        }
        if (k + 1 < NCH) commit((k + 1) & 1);
        __syncthreads();
    }

    const bool lane_ok = (ox < OW);
    if constexpr (EPI == 0) {
#pragma unroll
        for (int j = 0; j < OCW; ++j) {
            const int oc = woc0 + j;
            const float s = gam[oc] * BN_SCALE;
            const float bb = bet[oc];
            const float r = fmaxf(fmaf(acc[j], s, bb), 0.f);
            if (lane_ok)
                out[((size_t)(b * OC + oc) * OH + oy) * OW + ox] = r;
        }
    } else {
        float partial = 0.f;
#pragma unroll
        for (int j = 0; j < OCW; ++j) {
            const int oc = woc0 + j;
            const float s = gam[oc] * BN_SCALE;
            const float bb = bet[oc];
            const float r = fmaxf(fmaf(acc[j], s, bb), 0.f);
            partial = fmaf(r, w2[oc], partial);
        }
        red[wave][lane] = partial;
        __syncthreads();
        if (wave == 0 && lane_ok) {
            const float s = red[0][lane] + red[1][lane] + red[2][lane] + red[3][lane];
            atomicAdd(&out[(size_t)b * NPIX + (size_t)oy * OW + ox], s);
        }
    }
}

// ---------------- zero init: bev + head accumulators ----------------
__global__ void zero_init(float* __restrict__ bev, float* __restrict__ hma,
                          float* __restrict__ dla) {
    int i = blockIdx.x * blockDim.x + threadIdx.x;
    if (i < BB * BEV * BEV) bev[i] = 0.0f;
    if (i < BB * NPIX) { hma[i] = 0.0f; dla[i] = 0.0f; }
}

// ---------------- head finish: bias + sigmoid / depth transform ----------------
__global__ void heads_finish(const float* __restrict__ hma, const float* __restrict__ dla,
                             const float* __restrict__ bh2, const float* __restrict__ bd2,
                             float* __restrict__ out_hm, float* __restrict__ out_depth,
                             float* __restrict__ prob, float* __restrict__ depw) {
    int i = blockIdx.x * blockDim.x + threadIdx.x;
    if (i >= BB * NPIX) return;
    const float hm = hma[i] + bh2[0];
    out_hm[i] = hm;
    prob[i] = 1.0f / (1.0f + expf(-hm));
    const float dl = dla[i] + bd2[0];
    const float dep = 1.0f + (1.0f / (1.0f + expf(-dl))) * 79.0f;
    out_depth[i] = dep;
    depw[i] = dep;
}

// ---------------- select top-K SET by value-bisection + fused projection/splat ----
__global__ __launch_bounds__(1024) void select_splat(
        const float* __restrict__ prob, const float* __restrict__ depth,
        const float* __restrict__ camP, const float* __restrict__ camT,
        float* __restrict__ bev) {
    const int b = blockIdx.x;
    const int tid = threadIdx.x;
    const int lane = tid & 63, wave = tid >> 6;
    __shared__ unsigned sv[NPIX];
    __shared__ unsigned wcnt[16];
    __shared__ unsigned scan_w[16];
    __shared__ unsigned bcast;
    __shared__ int list[KTOP];
    __shared__ int nsel;

    for (int i = tid; i < NPIX; i += 1024) sv[i] = __float_as_uint(prob[(size_t)b * NPIX + i]);
    if (tid == 0) nsel = 0;
    __syncthreads();

    auto countGE = [&](unsigned t) -> unsigned {
        unsigned c = 0;
        for (int i = tid; i < NPIX; i += 1024) c += (sv[i] >= t) ? 1u : 0u;
#pragma unroll
        for (int off = 32; off; off >>= 1) c += __shfl_xor((int)c, off, 64);
        if (lane == 0) wcnt[wave] = c;
        __syncthreads();
        if (tid == 0) {
            unsigned tot = 0;
            for (int w = 0; w < 16; ++w) tot += wcnt[w];
            bcast = tot;
        }
        __syncthreads();
        unsigned tot = bcast;
        __syncthreads();
        return tot;
    };

    const unsigned THRB = 0x3E19999Au;          // __float_as_uint(0.15f)
    unsigned tstrict;
    unsigned need = 0;
    const unsigned c_thr = countGE(THRB);
    if (c_thr <= (unsigned)KTOP) {
        tstrict = THRB - 1u;
    } else {
        unsigned lo = THRB, hi = 0x3F800000u;
        while (lo < hi) {
            unsigned mid = lo + (hi - lo + 1u) / 2u;
            unsigned c = countGE(mid);
            if (c >= (unsigned)KTOP) lo = mid; else hi = mid - 1u;
        }
        tstrict = lo;
        need = (unsigned)KTOP - countGE(lo + 1u);
    }

    for (int i = tid; i < NPIX; i += 1024)
        if (sv[i] > tstrict) { int p = atomicAdd(&nsel, 1); list[p] = i; }
    __syncthreads();

    if (need > 0) {
        const unsigned tv = tstrict;
        const int CH = NPIX / 1024;
        const int i0 = tid * CH, i1 = i0 + CH;
        unsigned cnt = 0;
        for (int i = i0; i < i1; ++i) cnt += (sv[i] == tv) ? 1u : 0u;
        unsigned inc = cnt;
#pragma unroll
        for (int off = 1; off < 64; off <<= 1) {
            unsigned o = __shfl_up((int)inc, off, 64);
            if (lane >= off) inc += o;
        }
        if (lane == 63) scan_w[wave] = inc;
        __syncthreads();
        if (tid == 0) {
            unsigned s = 0;
            for (int w = 0; w < 16; ++w) { unsigned x = scan_w[w]; scan_w[w] = s; s += x; }
        }
        __syncthreads();
        unsigned r = inc - cnt + scan_w[wave];
        for (int i = i0; i < i1; ++i) {
            if (sv[i] == tv) {
                if (r < need) { int p = atomicAdd(&nsel, 1); list[p] = i; }
                ++r;
            }
        }
        __syncthreads();
    }

    const int ns = nsel;
    if (tid < ns) {
        const int idx = list[tid];
        const float score = __uint_as_float(sv[idx]);
        const int ys = idx / W3C, xs = idx % W3C;
        const float d = depth[(size_t)b * NPIX + idx];
        const float u = ((float)xs + 0.5f) * 8.0f;
        const float v = ((float)ys + 0.5f) * 8.0f;
        const float* P = camP + b * 12;
        const float fx = fmaxf(P[0], 1e-4f), fy = fmaxf(P[5], 1e-4f);
        const float cx = P[2], cy = P[6], tx = P[3], ty = P[7];
        const float x_cam = (u * d - cx * d - tx) / fx;
        const float y_cam = (v * d - cy * d - ty) / fy;
        const float* T = camT + b * 16;
        const float lx = T[0] * x_cam + T[1] * y_cam + T[2] * d + T[3];
        const float ly = T[4] * x_cam + T[5] * y_cam + T[6] * d + T[7];
        const int gx = (int)floorf((lx - (-51.2f)) / 0.2f);
        const int gy = (int)floorf((ly - (-51.2f)) / 0.2f);
        if (gx >= 0 && gx < BEV && gy >= 0 && gy < BEV) {
            int* bb = (int*)(bev + (size_t)b * BEV * BEV);
#pragma unroll
            for (int dy = -2; dy <= 2; ++dy) {
                const int iy = gy + dy;
                if (iy < 0 || iy >= BEV) continue;
#pragma unroll
                for (int dx = -2; dx <= 2; ++dx) {
                    const int ix = gx + dx;
                    if (ix < 0 || ix >= BEV) continue;
                    const float g = expf((float)(-(dy * dy + dx * dx)) / 1.3888888888888890f);
                    atomicMax(&bb[iy * BEV + ix], __float_as_int(score * g));
                }
            }
        }
    }
}

// ---------------- clip + logit ----------------
__global__ void bev_finish(const float* __restrict__ bev, float* __restrict__ out_logits,
                           float* __restrict__ out_prob) {
    int i = blockIdx.x * blockDim.x + threadIdx.x;
    if (i >= BB * BEV * BEV) return;
    float p = bev[i];
    p = fminf(fmaxf(p, 1e-4f), 0.9999f);
    out_logits[i] = logf(p) - log1pf(-p);
    out_prob[i] = p;
}

// ---------------- launcher ----------------
extern "C" void kernel_launch(void* const* d_in, const int* in_sizes, int n_in,
                              void* d_out, int out_size, void* d_ws, size_t ws_size,
                              hipStream_t stream) {
    (void)in_sizes; (void)n_in; (void)out_size; (void)ws_size;
    const float* image = (const float*)d_in[0];
    const float* camP  = (const float*)d_in[1];
    const float* camT  = (const float*)d_in[2];
    const float* W1  = (const float*)d_in[3];
    const float* g1  = (const float*)d_in[4];
    const float* b1  = (const float*)d_in[5];
    const float* W2  = (const float*)d_in[6];
    const float* g2  = (const float*)d_in[7];
    const float* b2  = (const float*)d_in[8];
    const float* W3  = (const float*)d_in[9];
    const float* g3  = (const float*)d_in[10];
    const float* b3  = (const float*)d_in[11];
    const float* Wh1 = (const float*)d_in[12];
    const float* gh1 = (const float*)d_in[13];
    const float* bh1 = (const float*)d_in[14];
    const float* Wh2 = (const float*)d_in[15];
    const float* bh2 = (const float*)d_in[16];
    const float* Wd1 = (const float*)d_in[17];
    const float* gd1 = (const float*)d_in[18];
    const float* bd1 = (const float*)d_in[19];
    const float* Wd2 = (const float*)d_in[20];
    const float* bd2 = (const float*)d_in[21];

    float* ws = (float*)d_ws;
    float* x1    = ws + OFF_X1;
    float* x2    = ws + OFF_X2;
    float* feats = ws + OFF_F;
    float* prob  = ws + OFF_PROB;
    float* depw  = ws + OFF_DEP;
    float* hma   = ws + OFF_HMA;
    float* dla   = ws + OFF_DLA;
    float* bev   = ws + OFF_BEV;

    float* out       = (float*)d_out;
    float* out_hm    = out;                                // [4,1,64,176]
    float* out_depth = out + (size_t)BB * NPIX;            // [4,1,64,176]
    float* out_lg    = out + (size_t)2 * BB * NPIX;        // [4,1,512,512]
    float* out_pr    = out_lg + (size_t)BB * BEV * BEV;    // [4,1,512,512]

    const int TPB = 256;
    // zero bev + head accumulators first (ws is poisoned before every launch)
    zero_init<<<(BB * BEV * BEV + TPB - 1) / TPB, TPB, 0, stream>>>(bev, hma, dla);

    // conv1: 3 -> 32, s2 (single cin chunk)
    conv3x3_tiled<3, 2, 32, 3, 0, 1><<<dim3(11, H1C, BB), 256, 0, stream>>>(
        image, W1, g1, b1, x1, nullptr, IMG_H, IMG_W, H1C, W1C);
    // conv2: 32 -> 64, s2
    conv3x3_tiled<32, 2, 64, 8, 0, 1><<<dim3(6, H2C, BB), 256, 0, stream>>>(
        x1, W2, g2, b2, x2, nullptr, H1C, W1C, H2C, W2C);
    // conv3: 64 -> 96, s2, oc-split x2 for occupancy
    conv3x3_tiled<64, 2, 96, 8, 0, 2><<<dim3(3 * 2, H3C, BB), 256, 0, stream>>>(
        x2, W3, g3, b3, feats, nullptr, H2C, W2C, H3C, W3C);
    // heatmap head: 96 -> 96 (s1) -> 1x1 partial -> atomicAdd(hma)  [CC=16: 6 chunks]
    conv3x3_tiled<96, 1, 96, 16, 1, 2><<<dim3(3 * 2, H3C, BB), 256, 0, stream>>>(
        feats, Wh1, gh1, bh1, hma, Wh2, H3C, W3C, H3C, W3C);
    // depth head: 96 -> 96 (s1) -> 1x1 partial -> atomicAdd(dla)   [CC=16: 6 chunks]
    conv3x3_tiled<96, 1, 96, 16, 1, 2><<<dim3(3 * 2, H3C, BB), 256, 0, stream>>>(
        feats, Wd1, gd1, bd1, dla, Wd2, H3C, W3C, H3C, W3C);
    // bias + sigmoid/depth transforms
    heads_finish<<<(BB * NPIX + TPB - 1) / TPB, TPB, 0, stream>>>(
        hma, dla, bh2, bd2, out_hm, out_depth, prob, depw);

    // BEV: select+splat -> finish
    select_splat<<<BB, 1024, 0, stream>>>(prob, depw, camP, camT, bev);
    bev_finish<<<(BB * BEV * BEV + TPB - 1) / TPB, TPB, 0, stream>>>(bev, out_lg, out_pr);
}

// Round 14
// 943.965 us; speedup vs baseline: 1.2273x; 1.0083x over previous
//
#include <hip/hip_runtime.h>
#include <math.h>

// ---------------- problem constants ----------------
static constexpr int BB = 4;
static constexpr int IMG_H = 512, IMG_W = 1408;
static constexpr int C1 = 32, H1C = 256, W1C = 704;
static constexpr int C2 = 64, H2C = 128, W2C = 352;
static constexpr int C3 = 96, H3C = 64,  W3C = 176;
static constexpr int NPIX = H3C * W3C;          // 11264
static constexpr int KTOP = 200;
static constexpr int BEV = 512;

// ---------------- workspace layout (floats) ----------------
static constexpr size_t SZ_X1   = (size_t)BB * C1 * H1C * W1C;
static constexpr size_t SZ_X2   = (size_t)BB * C2 * H2C * W2C;
static constexpr size_t SZ_HEAD = (size_t)BB * C3 * H3C * W3C;
static constexpr size_t OFF_X1   = 0;
static constexpr size_t OFF_X2   = SZ_X1;
static constexpr size_t OFF_F    = OFF_X2 + SZ_X2;
static constexpr size_t OFF_PROB = OFF_F + SZ_HEAD;
static constexpr size_t OFF_DEP  = OFF_PROB + (size_t)BB * NPIX;
static constexpr size_t OFF_HMA  = OFF_DEP + (size_t)BB * NPIX;   // hm-logit accum
static constexpr size_t OFF_DLA  = OFF_HMA + (size_t)BB * NPIX;   // depth-logit accum
static constexpr size_t OFF_BEV  = OFF_DLA + (size_t)BB * NPIX;   // float [BB*512*512]

// BN eval scale: 1/sqrt(1 + 1e-5)
static constexpr float BN_SCALE = 0.99999500003749973f;

// ---------------- tiled conv 3x3 (+BN+ReLU) with double-buffered LDS staging ----
// Block: 256 threads = 4 waves, 64 output columns (lane = ox), one output row.
// OCG splits the OC dimension across OCG blocks. Staging is reg-issued early
// and committed to the alternate LDS buffer after compute -> 1 barrier/chunk.
// EPI: 0 = store BN+ReLU conv output.
//      1 = BN+ReLU -> dot with w2 over this block's channels -> atomicAdd(out)
//          (out zero-initialized; OCG commutative f32 adds -> order-dependent
//          rounding bounded at ~2 ulp for OCG=4; selection-flip risk negligible)
// Measured history: R10 heads OCG=2 CC=8: 215us ea (occ 52%); R12 dual-head
// fusion: 642us REGRESSION (inst bloat); R13 CC=16: 220us NEUTRAL (occ 35%).
// R14: OCG=4 on heads -> 12 blocks/CU (grid) vs 11 (LDS cap) -> ~full occupancy.
template <int CIN, int STRIDE, int OC, int CC, int EPI, int OCG>
__global__ __launch_bounds__(256) void conv3x3_tiled(
        const float* __restrict__ in, const float* __restrict__ wg,
        const float* __restrict__ gam, const float* __restrict__ bet,
        float* __restrict__ out, const float* __restrict__ w2,
        int H, int W, int OH, int OW) {
    constexpr int OCW = OC / (4 * OCG);
    constexpr int SPAN = STRIDE * 64 + 2;     // 130 (s2) / 66 (s1)
    constexpr int ELEMS = CC * 3 * SPAN;
    constexpr int NLD = (ELEMS + 255) / 256;
    constexpr int NCH = CIN / CC;
    __shared__ float lds[2][ELEMS];
    __shared__ float red[4][64];

    const int xt = blockIdx.x / OCG, g = blockIdx.x % OCG;
    const int oy = blockIdx.y, b = blockIdx.z;
    const int t = threadIdx.x;
    const int lane = t & 63, wave = t >> 6;
    const int ox0 = xt * 64;
    const int ox = ox0 + lane;
    const int gx0 = ox0 * STRIDE - 1;
    const int li = STRIDE * lane;

    const int woc0 = (__builtin_amdgcn_readfirstlane(wave) + 4 * g) * OCW;
    const float* wbase = wg + (size_t)woc0 * CIN * 9;

    float acc[OCW];
#pragma unroll
    for (int j = 0; j < OCW; ++j) acc[j] = 0.f;

    float st[NLD];
    auto issue = [&](int cin0) {
#pragma unroll
        for (int l = 0; l < NLD; ++l) {
            const int i = t + l * 256;
            float v = 0.f;
            if (i < ELEMS) {
                const int cc = i / (3 * SPAN);
                const int rem = i % (3 * SPAN);
                const int r = rem / SPAN, x = rem % SPAN;
                const int gx = gx0 + x;
                const int iy = oy * STRIDE + r - 1;
                if (gx >= 0 && gx < W && iy >= 0 && iy < H)
                    v = in[((size_t)(b * CIN + cin0 + cc) * H + iy) * W + gx];
            }
            st[l] = v;
        }
    };
    auto commit = [&](int buf) {
#pragma unroll
        for (int l = 0; l < NLD; ++l) {
            const int i = t + l * 256;
            if (i < ELEMS) lds[buf][i] = st[l];
        }
    };

    issue(0);
    commit(0);
    __syncthreads();
    for (int k = 0; k < NCH; ++k) {
        const int cur = k & 1;
        if (k + 1 < NCH) issue((k + 1) * CC);
        const float* __restrict__ L = lds[cur];
#pragma unroll 2
        for (int cc = 0; cc < CC; ++cc) {
            const int cin = k * CC + cc;
#pragma unroll
            for (int kh = 0; kh < 3; ++kh) {
                const float v0 = L[(cc * 3 + kh) * SPAN + li + 0];
                const float v1 = L[(cc * 3 + kh) * SPAN + li + 1];
                const float v2 = L[(cc * 3 + kh) * SPAN + li + 2];
                const float* wp = wbase + cin * 9 + kh * 3;
#pragma unroll
                for (int j = 0; j < OCW; ++j) {
                    const float* wj = wp + (size_t)j * CIN * 9;
                    acc[j] = fmaf(v0, wj[0], acc[j]);
                    acc[j] = fmaf(v1, wj[1], acc[j]);
                    acc[j] = fmaf(v2, wj[2], acc[j]);
                }
            }
        }
        if (k + 1 < NCH) commit((k + 1) & 1);
        __syncthreads();
    }

    const bool lane_ok = (ox < OW);
    if constexpr (EPI == 0) {
#pragma unroll
        for (int j = 0; j < OCW; ++j) {
            const int oc = woc0 + j;
            const float s = gam[oc] * BN_SCALE;
            const float bb = bet[oc];
            const float r = fmaxf(fmaf(acc[j], s, bb), 0.f);
            if (lane_ok)
                out[((size_t)(b * OC + oc) * OH + oy) * OW + ox] = r;
        }
    } else {
        float partial = 0.f;
#pragma unroll
        for (int j = 0; j < OCW; ++j) {
            const int oc = woc0 + j;
            const float s = gam[oc] * BN_SCALE;
            const float bb = bet[oc];
            const float r = fmaxf(fmaf(acc[j], s, bb), 0.f);
            partial = fmaf(r, w2[oc], partial);
        }
        red[wave][lane] = partial;
        __syncthreads();
        if (wave == 0 && lane_ok) {
            const float s = red[0][lane] + red[1][lane] + red[2][lane] + red[3][lane];
            atomicAdd(&out[(size_t)b * NPIX + (size_t)oy * OW + ox], s);
        }
    }
}

// ---------------- zero init: bev + head accumulators ----------------
__global__ void zero_init(float* __restrict__ bev, float* __restrict__ hma,
                          float* __restrict__ dla) {
    int i = blockIdx.x * blockDim.x + threadIdx.x;
    if (i < BB * BEV * BEV) bev[i] = 0.0f;
    if (i < BB * NPIX) { hma[i] = 0.0f; dla[i] = 0.0f; }
}

// ---------------- head finish: bias + sigmoid / depth transform ----------------
__global__ void heads_finish(const float* __restrict__ hma, const float* __restrict__ dla,
                             const float* __restrict__ bh2, const float* __restrict__ bd2,
                             float* __restrict__ out_hm, float* __restrict__ out_depth,
                             float* __restrict__ prob, float* __restrict__ depw) {
    int i = blockIdx.x * blockDim.x + threadIdx.x;
    if (i >= BB * NPIX) return;
    const float hm = hma[i] + bh2[0];
    out_hm[i] = hm;
    prob[i] = 1.0f / (1.0f + expf(-hm));
    const float dl = dla[i] + bd2[0];
    const float dep = 1.0f + (1.0f / (1.0f + expf(-dl))) * 79.0f;
    out_depth[i] = dep;
    depw[i] = dep;
}

// ---------------- select top-K SET by value-bisection + fused projection/splat ----
__global__ __launch_bounds__(1024) void select_splat(
        const float* __restrict__ prob, const float* __restrict__ depth,
        const float* __restrict__ camP, const float* __restrict__ camT,
        float* __restrict__ bev) {
    const int b = blockIdx.x;
    const int tid = threadIdx.x;
    const int lane = tid & 63, wave = tid >> 6;
    __shared__ unsigned sv[NPIX];
    __shared__ unsigned wcnt[16];
    __shared__ unsigned scan_w[16];
    __shared__ unsigned bcast;
    __shared__ int list[KTOP];
    __shared__ int nsel;

    for (int i = tid; i < NPIX; i += 1024) sv[i] = __float_as_uint(prob[(size_t)b * NPIX + i]);
    if (tid == 0) nsel = 0;
    __syncthreads();

    auto countGE = [&](unsigned t) -> unsigned {
        unsigned c = 0;
        for (int i = tid; i < NPIX; i += 1024) c += (sv[i] >= t) ? 1u : 0u;
#pragma unroll
        for (int off = 32; off; off >>= 1) c += __shfl_xor((int)c, off, 64);
        if (lane == 0) wcnt[wave] = c;
        __syncthreads();
        if (tid == 0) {
            unsigned tot = 0;
            for (int w = 0; w < 16; ++w) tot += wcnt[w];
            bcast = tot;
        }
        __syncthreads();
        unsigned tot = bcast;
        __syncthreads();
        return tot;
    };

    const unsigned THRB = 0x3E19999Au;          // __float_as_uint(0.15f)
    unsigned tstrict;
    unsigned need = 0;
    const unsigned c_thr = countGE(THRB);
    if (c_thr <= (unsigned)KTOP) {
        tstrict = THRB - 1u;
    } else {
        unsigned lo = THRB, hi = 0x3F800000u;
        while (lo < hi) {
            unsigned mid = lo + (hi - lo + 1u) / 2u;
            unsigned c = countGE(mid);
            if (c >= (unsigned)KTOP) lo = mid; else hi = mid - 1u;
        }
        tstrict = lo;
        need = (unsigned)KTOP - countGE(lo + 1u);
    }

    for (int i = tid; i < NPIX; i += 1024)
        if (sv[i] > tstrict) { int p = atomicAdd(&nsel, 1); list[p] = i; }
    __syncthreads();

    if (need > 0) {
        const unsigned tv = tstrict;
        const int CH = NPIX / 1024;
        const int i0 = tid * CH, i1 = i0 + CH;
        unsigned cnt = 0;
        for (int i = i0; i < i1; ++i) cnt += (sv[i] == tv) ? 1u : 0u;
        unsigned inc = cnt;
#pragma unroll
        for (int off = 1; off < 64; off <<= 1) {
            unsigned o = __shfl_up((int)inc, off, 64);
            if (lane >= off) inc += o;
        }
        if (lane == 63) scan_w[wave] = inc;
        __syncthreads();
        if (tid == 0) {
            unsigned s = 0;
            for (int w = 0; w < 16; ++w) { unsigned x = scan_w[w]; scan_w[w] = s; s += x; }
        }
        __syncthreads();
        unsigned r = inc - cnt + scan_w[wave];
        for (int i = i0; i < i1; ++i) {
            if (sv[i] == tv) {
                if (r < need) { int p = atomicAdd(&nsel, 1); list[p] = i; }
                ++r;
            }
        }
        __syncthreads();
    }

    const int ns = nsel;
    if (tid < ns) {
        const int idx = list[tid];
        const float score = __uint_as_float(sv[idx]);
        const int ys = idx / W3C, xs = idx % W3C;
        const float d = depth[(size_t)b * NPIX + idx];
        const float u = ((float)xs + 0.5f) * 8.0f;
        const float v = ((float)ys + 0.5f) * 8.0f;
        const float* P = camP + b * 12;
        const float fx = fmaxf(P[0], 1e-4f), fy = fmaxf(P[5], 1e-4f);
        const float cx = P[2], cy = P[6], tx = P[3], ty = P[7];
        const float x_cam = (u * d - cx * d - tx) / fx;
        const float y_cam = (v * d - cy * d - ty) / fy;
        const float* T = camT + b * 16;
        const float lx = T[0] * x_cam + T[1] * y_cam + T[2] * d + T[3];
        const float ly = T[4] * x_cam + T[5] * y_cam + T[6] * d + T[7];
        const int gx = (int)floorf((lx - (-51.2f)) / 0.2f);
        const int gy = (int)floorf((ly - (-51.2f)) / 0.2f);
        if (gx >= 0 && gx < BEV && gy >= 0 && gy < BEV) {
            int* bb = (int*)(bev + (size_t)b * BEV * BEV);
#pragma unroll
            for (int dy = -2; dy <= 2; ++dy) {
                const int iy = gy + dy;
                if (iy < 0 || iy >= BEV) continue;
#pragma unroll
                for (int dx = -2; dx <= 2; ++dx) {
                    const int ix = gx + dx;
                    if (ix < 0 || ix >= BEV) continue;
                    const float g = expf((float)(-(dy * dy + dx * dx)) / 1.3888888888888890f);
                    atomicMax(&bb[iy * BEV + ix], __float_as_int(score * g));
                }
            }
        }
    }
}

// ---------------- clip + logit ----------------
__global__ void bev_finish(const float* __restrict__ bev, float* __restrict__ out_logits,
                           float* __restrict__ out_prob) {
    int i = blockIdx.x * blockDim.x + threadIdx.x;
    if (i >= BB * BEV * BEV) return;
    float p = bev[i];
    p = fminf(fmaxf(p, 1e-4f), 0.9999f);
    out_logits[i] = logf(p) - log1pf(-p);
    out_prob[i] = p;
}

// ---------------- launcher ----------------
extern "C" void kernel_launch(void* const* d_in, const int* in_sizes, int n_in,
                              void* d_out, int out_size, void* d_ws, size_t ws_size,
                              hipStream_t stream) {
    (void)in_sizes; (void)n_in; (void)out_size; (void)ws_size;
    const float* image = (const float*)d_in[0];
    const float* camP  = (const float*)d_in[1];
    const float* camT  = (const float*)d_in[2];
    const float* W1  = (const float*)d_in[3];
    const float* g1  = (const float*)d_in[4];
    const float* b1  = (const float*)d_in[5];
    const float* W2  = (const float*)d_in[6];
    const float* g2  = (const float*)d_in[7];
    const float* b2  = (const float*)d_in[8];
    const float* W3  = (const float*)d_in[9];
    const float* g3  = (const float*)d_in[10];
    const float* b3  = (const float*)d_in[11];
    const float* Wh1 = (const float*)d_in[12];
    const float* gh1 = (const float*)d_in[13];
    const float* bh1 = (const float*)d_in[14];
    const float* Wh2 = (const float*)d_in[15];
    const float* bh2 = (const float*)d_in[16];
    const float* Wd1 = (const float*)d_in[17];
    const float* gd1 = (const float*)d_in[18];
    const float* bd1 = (const float*)d_in[19];
    const float* Wd2 = (const float*)d_in[20];
    const float* bd2 = (const float*)d_in[21];

    float* ws = (float*)d_ws;
    float* x1    = ws + OFF_X1;
    float* x2    = ws + OFF_X2;
    float* feats = ws + OFF_F;
    float* prob  = ws + OFF_PROB;
    float* depw  = ws + OFF_DEP;
    float* hma   = ws + OFF_HMA;
    float* dla   = ws + OFF_DLA;
    float* bev   = ws + OFF_BEV;

    float* out       = (float*)d_out;
    float* out_hm    = out;                                // [4,1,64,176]
    float* out_depth = out + (size_t)BB * NPIX;            // [4,1,64,176]
    float* out_lg    = out + (size_t)2 * BB * NPIX;        // [4,1,512,512]
    float* out_pr    = out_lg + (size_t)BB * BEV * BEV;    // [4,1,512,512]

    const int TPB = 256;
    // zero bev + head accumulators first (ws is poisoned before every launch)
    zero_init<<<(BB * BEV * BEV + TPB - 1) / TPB, TPB, 0, stream>>>(bev, hma, dla);

    // conv1: 3 -> 32, s2 (single cin chunk)
    conv3x3_tiled<3, 2, 32, 3, 0, 1><<<dim3(11, H1C, BB), 256, 0, stream>>>(
        image, W1, g1, b1, x1, nullptr, IMG_H, IMG_W, H1C, W1C);
    // conv2: 32 -> 64, s2
    conv3x3_tiled<32, 2, 64, 8, 0, 1><<<dim3(6, H2C, BB), 256, 0, stream>>>(
        x1, W2, g2, b2, x2, nullptr, H1C, W1C, H2C, W2C);
    // conv3: 64 -> 96, s2, oc-split x2 (x4 buys nothing: LDS caps at 6 blocks/CU)
    conv3x3_tiled<64, 2, 96, 8, 0, 2><<<dim3(3 * 2, H3C, BB), 256, 0, stream>>>(
        x2, W3, g3, b3, feats, nullptr, H2C, W2C, H3C, W3C);
    // heatmap head: 96 -> 96 (s1) -> 1x1 partial -> atomicAdd(hma)  [OCG=4: 12 blk/CU]
    conv3x3_tiled<96, 1, 96, 8, 1, 4><<<dim3(3 * 4, H3C, BB), 256, 0, stream>>>(
        feats, Wh1, gh1, bh1, hma, Wh2, H3C, W3C, H3C, W3C);
    // depth head: 96 -> 96 (s1) -> 1x1 partial -> atomicAdd(dla)   [OCG=4]
    conv3x3_tiled<96, 1, 96, 8, 1, 4><<<dim3(3 * 4, H3C, BB), 256, 0, stream>>>(
        feats, Wd1, gd1, bd1, dla, Wd2, H3C, W3C, H3C, W3C);
    // bias + sigmoid/depth transforms
    heads_finish<<<(BB * NPIX + TPB - 1) / TPB, TPB, 0, stream>>>(
        hma, dla, bh2, bd2, out_hm, out_depth, prob, depw);

    // BEV: select+splat -> finish
    select_splat<<<BB, 1024, 0, stream>>>(prob, depw, camP, camT, bev);
    bev_finish<<<(BB * BEV * BEV + TPB - 1) / TPB, TPB, 0, stream>>>(bev, out_lg, out_pr);
}